// Round 1
// baseline (70.814 us; speedup 1.0000x reference)
//
#include <hip/hip_runtime.h>
#include <math.h>

// Problem constants (fixed by setup_inputs)
constexpr int kB = 32;         // batch
constexpr int kS = 128;        // seq len
constexpr int kD = 256;        // hidden
constexpr int kK = 8;          // window
constexpr int kNPair = 2104;   // pairs with |j-i|<=8
constexpr int kInDim = 2 * kD + 64;  // 576
constexpr int kRows = kB * kS;       // 4096

// ---------------------------------------------------------------------------
// Kernel A: R[t][d] = sum_u (128-|u-8|) * exp(-(t-u)^2) * (pos_emb[u] . W1c[d]) + b1[d]
// One block, 256 threads (thread = output dim d).
// ---------------------------------------------------------------------------
__global__ __launch_bounds__(256) void build_R(const float* __restrict__ pos_emb,
                                               const float* __restrict__ W1,
                                               const float* __restrict__ b1,
                                               float* __restrict__ R) {
  __shared__ float pe[17 * 64];
  const int tid = threadIdx.x;
  for (int idx = tid; idx < 17 * 64; idx += 256) pe[idx] = pos_emb[idx];
  __syncthreads();
  const int d = tid;
  // cache W1c row (64 floats) in registers
  float w[64];
  const float* wr = W1 + d * kInDim + 2 * kD;
#pragma unroll
  for (int q = 0; q < 16; ++q) {
    float4 t4 = *(const float4*)(wr + q * 4);
    w[q * 4 + 0] = t4.x; w[q * 4 + 1] = t4.y;
    w[q * 4 + 2] = t4.z; w[q * 4 + 3] = t4.w;
  }
  float acc[17];
#pragma unroll
  for (int t = 0; t < 17; ++t) acc[t] = 0.f;
  for (int u = 0; u < 17; ++u) {
    float m = 0.f;
#pragma unroll
    for (int p = 0; p < 64; ++p) m += pe[u * 64 + p] * w[p];
    int au = u - kK; if (au < 0) au = -au;
    m *= (float)(kS - au);   // fold count of pairs with this rel value
#pragma unroll
    for (int t = 0; t < 17; ++t) {
      int dd = t - u;
      acc[t] += expf((float)(-(dd * dd))) * m;
    }
  }
#pragma unroll
  for (int t = 0; t < 17; ++t) R[t * kD + d] = acc[t] + b1[d];
}

// ---------------------------------------------------------------------------
// Kernel B: U[r][d] = H[r] . W1[d][0:256],  V[r][d] = H[r] . W1[d][256:512]
// Treated as one GEMM: out[4096][512] = H[4096][256] * Wcat[512][256]^T
// 64x64 block tile, BK=32, 256 threads, 4x4 micro-tile.
// ---------------------------------------------------------------------------
constexpr int BM = 64, BN = 64, BK = 32;

__global__ __launch_bounds__(256) void gemm_uv(const float* __restrict__ H,
                                               const float* __restrict__ W1,
                                               float* __restrict__ U,
                                               float* __restrict__ V) {
  __shared__ __align__(16) float As[BK][BM];
  __shared__ __align__(16) float Bs[BK][BN];
  const int tid = threadIdx.x;
  const int mt = blockIdx.x;
  const int nt = blockIdx.y;
  const int tm = (tid & 15) * 4;
  const int tn = (tid >> 4) * 4;
  float acc[4][4];
#pragma unroll
  for (int a = 0; a < 4; ++a)
#pragma unroll
    for (int b = 0; b < 4; ++b) acc[a][b] = 0.f;

  for (int k0 = 0; k0 < kD; k0 += BK) {
#pragma unroll
    for (int l = 0; l < 2; ++l) {
      int idx = tid + l * 256;       // 0..511
      int row = idx >> 3;            // 0..63
      int kq  = (idx & 7) * 4;       // 0,4,...,28
      float4 a4 = *(const float4*)(H + (mt * BM + row) * kD + k0 + kq);
      As[kq + 0][row] = a4.x; As[kq + 1][row] = a4.y;
      As[kq + 2][row] = a4.z; As[kq + 3][row] = a4.w;
      int c = nt * BN + row;         // output column (0..511)
      const float* wrow = W1 + (c & 255) * kInDim + ((c < kD) ? 0 : kD);
      float4 b4 = *(const float4*)(wrow + k0 + kq);
      Bs[kq + 0][row] = b4.x; Bs[kq + 1][row] = b4.y;
      Bs[kq + 2][row] = b4.z; Bs[kq + 3][row] = b4.w;
    }
    __syncthreads();
#pragma unroll
    for (int kk = 0; kk < BK; ++kk) {
      float4 a4 = *(const float4*)&As[kk][tm];
      float4 b4 = *(const float4*)&Bs[kk][tn];
      float av[4] = {a4.x, a4.y, a4.z, a4.w};
      float bv[4] = {b4.x, b4.y, b4.z, b4.w};
#pragma unroll
      for (int a = 0; a < 4; ++a)
#pragma unroll
        for (int b = 0; b < 4; ++b) acc[a][b] += av[a] * bv[b];
    }
    __syncthreads();
  }
#pragma unroll
  for (int a = 0; a < 4; ++a) {
    int r = mt * BM + tm + a;
    int cbase = nt * BN + tn;
    float4 o;
    o.x = acc[a][0]; o.y = acc[a][1]; o.z = acc[a][2]; o.w = acc[a][3];
    if (cbase < kD) {
      *(float4*)(U + r * kD + cbase) = o;
    } else {
      *(float4*)(V + r * kD + (cbase - kD)) = o;
    }
  }
}

// ---------------------------------------------------------------------------
// Kernel C: one wave (64 lanes) per pair (b,i,j): h = U[b,i]+V[b,j]+R[rel],
// LayerNorm, ELU, dot W2 -> score. Lane 0 of b==0 waves also writes positions.
// Pair index p recovered in closed form (no search).
// ---------------------------------------------------------------------------
__global__ __launch_bounds__(256) void pair_score(
    const float* __restrict__ U, const float* __restrict__ V,
    const float* __restrict__ R,
    const float* __restrict__ ln_g, const float* __restrict__ ln_b,
    const float* __restrict__ W2, const float* __restrict__ b2,
    float* __restrict__ out) {
  const int gtid = blockIdx.x * 256 + threadIdx.x;
  const int wid = gtid >> 6;          // global wave id over (b, i, t)
  const int lane = threadIdx.x & 63;
  const int t = wid % 17;             // t = rel + 8
  const int bi = wid / 17;
  const int i = bi & (kS - 1);
  const int b = bi >> 7;
  if (b >= kB) return;
  const int j = i - kK + t;
  if (j < 0 || j >= kS) return;       // wave-uniform early-out
  // closed-form prefix: start[i] = # pairs with row < i
  int start_i;
  if (i <= 8)        start_i = (i * i + 17 * i) / 2;
  else if (i <= 120) start_i = 100 + (i - 8) * 17;
  else { int m = i - 120; start_i = 2004 + 16 * m - (m * (m - 1)) / 2; }
  const int lower = (i - kK > 0) ? (i - kK) : 0;
  const int p = start_i + (j - lower);

  const int d0 = lane * 4;
  float4 u4 = *(const float4*)(U + (b * kS + i) * kD + d0);
  float4 v4 = *(const float4*)(V + (b * kS + j) * kD + d0);
  float4 r4 = *(const float4*)(R + t * kD + d0);
  float h0 = u4.x + v4.x + r4.x;
  float h1 = u4.y + v4.y + r4.y;
  float h2 = u4.z + v4.z + r4.z;
  float h3 = u4.w + v4.w + r4.w;
  float s = h0 + h1 + h2 + h3;
#pragma unroll
  for (int off = 32; off > 0; off >>= 1) s += __shfl_xor(s, off);
  const float mu = s * (1.0f / kD);
  float e0 = h0 - mu, e1 = h1 - mu, e2 = h2 - mu, e3 = h3 - mu;
  float vs = e0 * e0 + e1 * e1 + e2 * e2 + e3 * e3;
#pragma unroll
  for (int off = 32; off > 0; off >>= 1) vs += __shfl_xor(vs, off);
  const float rs = rsqrtf(vs * (1.0f / kD) + 1e-5f);
  float4 g4 = *(const float4*)(ln_g + d0);
  float4 be4 = *(const float4*)(ln_b + d0);
  float4 w4 = *(const float4*)(W2 + d0);
  float y0 = e0 * rs * g4.x + be4.x;
  float y1 = e1 * rs * g4.y + be4.y;
  float y2 = e2 * rs * g4.z + be4.z;
  float y3 = e3 * rs * g4.w + be4.w;
  y0 = y0 > 0.f ? y0 : expm1f(y0);   // elu (alpha=1)
  y1 = y1 > 0.f ? y1 : expm1f(y1);
  y2 = y2 > 0.f ? y2 : expm1f(y2);
  y3 = y3 > 0.f ? y3 : expm1f(y3);
  float dot = y0 * w4.x + y1 * w4.y + y2 * w4.z + y3 * w4.w;
#pragma unroll
  for (int off = 32; off > 0; off >>= 1) dot += __shfl_xor(dot, off);
  if (lane == 0) {
    out[b * kNPair + p] = dot + b2[0];
    if (b == 0) {
      float* posout = out + kB * kNPair;   // positions written as f32 values
      posout[p * 2 + 0] = (float)(i + 1);
      posout[p * 2 + 1] = (float)(j + 1);
    }
  }
}

// ---------------------------------------------------------------------------
extern "C" void kernel_launch(void* const* d_in, const int* in_sizes, int n_in,
                              void* d_out, int out_size, void* d_ws, size_t ws_size,
                              hipStream_t stream) {
  const float* H       = (const float*)d_in[0];  // [32,128,256]
  const float* pos_emb = (const float*)d_in[1];  // [17,64]
  const float* W1      = (const float*)d_in[2];  // [256,576]
  const float* b1      = (const float*)d_in[3];  // [256]
  const float* ln_g    = (const float*)d_in[4];  // [256]
  const float* ln_b    = (const float*)d_in[5];  // [256]
  const float* W2      = (const float*)d_in[6];  // [1,256]
  const float* b2      = (const float*)d_in[7];  // [1]
  float* out = (float*)d_out;

  float* U = (float*)d_ws;            // [4096,256]  4 MB
  float* V = U + kRows * kD;          // [4096,256]  4 MB
  float* R = V + kRows * kD;          // [17,256]

  build_R<<<1, 256, 0, stream>>>(pos_emb, W1, b1, R);
  gemm_uv<<<dim3(kRows / BM, (2 * kD) / BN), 256, 0, stream>>>(H, W1, U, V);
  const int n_waves = kB * kS * 17;   // 69632 (includes out-of-range j, masked)
  pair_score<<<n_waves / 4, 256, 0, stream>>>(U, V, R, ln_g, ln_b, W2, b2, out);
}

// Round 2
// 50.739 us; speedup vs baseline: 1.3957x; 1.3957x over previous
//
#include <hip/hip_runtime.h>
#include <math.h>

// Problem constants (fixed by setup_inputs)
constexpr int kB = 32;         // batch
constexpr int kS = 128;        // seq len
constexpr int kD = 256;        // hidden
constexpr int kK = 8;          // window
constexpr int kNPair = 2104;   // pairs with |j-i|<=8
constexpr int kInDim = 2 * kD + 64;  // 576
constexpr int kRows = kB * kS;       // 4096

typedef __attribute__((ext_vector_type(8))) short short8;   // 8 bf16 (4 VGPRs)
typedef __attribute__((ext_vector_type(4))) float f32x4;    // MFMA C/D frag

// f32 -> bf16, round-to-nearest-even (inputs are normal floats; no NaN path)
__device__ inline ushort f2b(float f) {
  union { float f; uint u; } v; v.f = f;
  uint r = v.u + 0x7FFF + ((v.u >> 16) & 1);
  return (ushort)(r >> 16);
}

// ---------------------------------------------------------------------------
// Kernel AB (fused): blocks 0..511 do the bf16-MFMA GEMM
//   C[4096][512] = H[4096][256] x Wcat[512][256]^T   (U = cols 0:256, V = rest)
// block 512 computes R[t][d] = sum_u (128-|u-8|)*exp(-(t-u)^2)*(pos_emb[u].W1c[d]) + b1[d]
// GEMM: 64x64 tile, full K=256 in one LDS stage (bf16, XOR-swizzled), 4 waves,
// each wave 32x32 via 2x2 mfma_f32_16x16x32_bf16 frags.
// ---------------------------------------------------------------------------
__global__ __launch_bounds__(256) void gemm_uv_r(
    const float* __restrict__ H, const float* __restrict__ W1,
    const float* __restrict__ pos_emb, const float* __restrict__ b1,
    float* __restrict__ U, float* __restrict__ V, float* __restrict__ R) {
  __shared__ ushort As[64 * 256];   // 32 KB
  __shared__ ushort Bs[64 * 256];   // 32 KB
  const int tid = threadIdx.x;

  if (blockIdx.x == 512) {
    // ---- build_R (one block) ----
    float* pe = (float*)As;  // 17*64 floats, reuse LDS
    for (int idx = tid; idx < 17 * 64; idx += 256) pe[idx] = pos_emb[idx];
    __syncthreads();
    const int d = tid;
    float w[64];
    const float* wr = W1 + d * kInDim + 2 * kD;
#pragma unroll
    for (int q = 0; q < 16; ++q) {
      float4 t4 = *(const float4*)(wr + q * 4);
      w[q * 4 + 0] = t4.x; w[q * 4 + 1] = t4.y;
      w[q * 4 + 2] = t4.z; w[q * 4 + 3] = t4.w;
    }
    float acc[17];
#pragma unroll
    for (int t = 0; t < 17; ++t) acc[t] = 0.f;
    for (int u = 0; u < 17; ++u) {
      float m = 0.f;
#pragma unroll
      for (int p = 0; p < 64; ++p) m += pe[u * 64 + p] * w[p];
      int au = u - kK; if (au < 0) au = -au;
      m *= (float)(kS - au);
#pragma unroll
      for (int t = 0; t < 17; ++t) {
        int dd = t - u;
        acc[t] += expf((float)(-(dd * dd))) * m;
      }
    }
#pragma unroll
    for (int t = 0; t < 17; ++t) R[t * kD + d] = acc[t] + b1[d];
    return;
  }

  // ---- GEMM ----
  const int mt = blockIdx.x & 63;       // M tile (64 rows of H)
  const int nt = blockIdx.x >> 6;       // N tile (64 output cols of 512)
  const int m0 = mt * 64;
  const int side = (nt >= 4) ? kD : 0;  // U-half vs V-half of W1 rows
  const int wbase = (nt & 3) * 64;      // W1 row base within the 256

  // Stage both tiles: f32 global -> bf16 LDS, XOR-swizzled (bits 3-5 of
  // the ushort index within a row, keyed by row&7) so ds_read_b128 of a
  // 16-row column slice is ~2-way (free) instead of 16-way conflicted.
#pragma unroll
  for (int l = 0; l < 16; ++l) {
    int c = tid + l * 256;       // 0..4095 float4-chunks
    int row = c >> 6;            // 0..63
    int kq = (c & 63) << 2;      // element offset 0..252
    int sw = (row << 8) + (kq ^ ((row & 7) << 3));
    float4 a4 = *(const float4*)(H + (m0 + row) * kD + kq);
    ushort4 au; au.x = f2b(a4.x); au.y = f2b(a4.y); au.z = f2b(a4.z); au.w = f2b(a4.w);
    *(ushort4*)(As + sw) = au;
    float4 b4 = *(const float4*)(W1 + (wbase + row) * kInDim + side + kq);
    ushort4 bu; bu.x = f2b(b4.x); bu.y = f2b(b4.y); bu.z = f2b(b4.z); bu.w = f2b(b4.w);
    *(ushort4*)(Bs + sw) = bu;
  }
  __syncthreads();

  const int lane = tid & 63;
  const int w = tid >> 6;            // wave 0..3
  const int wm = (w & 1) * 32;
  const int wn = (w >> 1) * 32;
  const int lr = lane & 15;
  const int lk = (lane >> 4) * 8;

  f32x4 acc[2][2] = {{{0.f,0.f,0.f,0.f},{0.f,0.f,0.f,0.f}},
                     {{0.f,0.f,0.f,0.f},{0.f,0.f,0.f,0.f}}};
#pragma unroll
  for (int kk = 0; kk < 8; ++kk) {
    const int k0 = kk * 32 + lk;
    short8 a[2], b[2];
#pragma unroll
    for (int mf = 0; mf < 2; ++mf) {
      int ra = wm + mf * 16 + lr;
      a[mf] = *(const short8*)(const void*)(As + (ra << 8) + (k0 ^ ((ra & 7) << 3)));
      int rb = wn + mf * 16 + lr;
      b[mf] = *(const short8*)(const void*)(Bs + (rb << 8) + (k0 ^ ((rb & 7) << 3)));
    }
#pragma unroll
    for (int mf = 0; mf < 2; ++mf)
#pragma unroll
      for (int nf = 0; nf < 2; ++nf)
        acc[mf][nf] = __builtin_amdgcn_mfma_f32_16x16x32_bf16(a[mf], b[nf], acc[mf][nf], 0, 0, 0);
  }

  // C/D frag mapping (m89): col = lane&15, row = (lane>>4)*4 + reg
  const int rowg0 = m0 + wm + (lane >> 4) * 4;
  const int colg0 = nt * 64 + wn + lr;
#pragma unroll
  for (int mf = 0; mf < 2; ++mf)
#pragma unroll
    for (int nf = 0; nf < 2; ++nf) {
      int colg = colg0 + nf * 16;
      float* dst = (colg < kD) ? (U + colg) : (V + (colg - kD));
#pragma unroll
      for (int r = 0; r < 4; ++r) {
        int rowg = rowg0 + mf * 16 + r;
        dst[rowg * kD] = acc[mf][nf][r];
      }
    }
}

// ---------------------------------------------------------------------------
// Kernel C: one wave per pair (b,i,j): h = U[b,i]+V[b,j]+R[rel], LayerNorm
// (fused sum+sumsq reduction), ELU, dot W2 -> score.
// ---------------------------------------------------------------------------
__global__ __launch_bounds__(256) void pair_score(
    const float* __restrict__ U, const float* __restrict__ V,
    const float* __restrict__ R,
    const float* __restrict__ ln_g, const float* __restrict__ ln_b,
    const float* __restrict__ W2, const float* __restrict__ b2,
    float* __restrict__ out) {
  const int gtid = blockIdx.x * 256 + threadIdx.x;
  const int wid = gtid >> 6;          // global wave id over (b, i, t)
  const int lane = threadIdx.x & 63;
  const int t = wid % 17;             // t = rel + 8
  const int bi = wid / 17;
  const int i = bi & (kS - 1);
  const int b = bi >> 7;
  if (b >= kB) return;
  const int j = i - kK + t;
  if (j < 0 || j >= kS) return;       // wave-uniform early-out
  // closed-form prefix: start[i] = # pairs with emo row < i
  int start_i;
  if (i <= 8)        start_i = (i * i + 17 * i) / 2;
  else if (i <= 120) start_i = 100 + (i - 8) * 17;
  else { int m = i - 120; start_i = 2004 + 16 * m - (m * (m - 1)) / 2; }
  const int lower = (i - kK > 0) ? (i - kK) : 0;
  const int p = start_i + (j - lower);

  const int d0 = lane * 4;
  float4 u4 = *(const float4*)(U + (b * kS + i) * kD + d0);
  float4 v4 = *(const float4*)(V + (b * kS + j) * kD + d0);
  float4 r4 = *(const float4*)(R + t * kD + d0);
  float h0 = u4.x + v4.x + r4.x;
  float h1 = u4.y + v4.y + r4.y;
  float h2 = u4.z + v4.z + r4.z;
  float h3 = u4.w + v4.w + r4.w;
  float s = h0 + h1 + h2 + h3;
  float q = h0 * h0 + h1 * h1 + h2 * h2 + h3 * h3;
#pragma unroll
  for (int off = 32; off > 0; off >>= 1) {
    s += __shfl_xor(s, off);
    q += __shfl_xor(q, off);
  }
  const float mu = s * (1.0f / kD);
  const float var = q * (1.0f / kD) - mu * mu;
  const float rs = rsqrtf(var + 1e-5f);
  float e0 = h0 - mu, e1 = h1 - mu, e2 = h2 - mu, e3 = h3 - mu;
  float4 g4 = *(const float4*)(ln_g + d0);
  float4 be4 = *(const float4*)(ln_b + d0);
  float4 w4 = *(const float4*)(W2 + d0);
  float y0 = e0 * rs * g4.x + be4.x;
  float y1 = e1 * rs * g4.y + be4.y;
  float y2 = e2 * rs * g4.z + be4.z;
  float y3 = e3 * rs * g4.w + be4.w;
  y0 = y0 > 0.f ? y0 : expm1f(y0);   // elu (alpha=1)
  y1 = y1 > 0.f ? y1 : expm1f(y1);
  y2 = y2 > 0.f ? y2 : expm1f(y2);
  y3 = y3 > 0.f ? y3 : expm1f(y3);
  float dot = y0 * w4.x + y1 * w4.y + y2 * w4.z + y3 * w4.w;
#pragma unroll
  for (int off = 32; off > 0; off >>= 1) dot += __shfl_xor(dot, off);
  if (lane == 0) {
    out[b * kNPair + p] = dot + b2[0];
    if (b == 0) {
      float* posout = out + kB * kNPair;   // positions read back as f32
      posout[p * 2 + 0] = (float)(i + 1);
      posout[p * 2 + 1] = (float)(j + 1);
    }
  }
}

// ---------------------------------------------------------------------------
extern "C" void kernel_launch(void* const* d_in, const int* in_sizes, int n_in,
                              void* d_out, int out_size, void* d_ws, size_t ws_size,
                              hipStream_t stream) {
  const float* H       = (const float*)d_in[0];  // [32,128,256]
  const float* pos_emb = (const float*)d_in[1];  // [17,64]
  const float* W1      = (const float*)d_in[2];  // [256,576]
  const float* b1      = (const float*)d_in[3];  // [256]
  const float* ln_g    = (const float*)d_in[4];  // [256]
  const float* ln_b    = (const float*)d_in[5];  // [256]
  const float* W2      = (const float*)d_in[6];  // [1,256]
  const float* b2      = (const float*)d_in[7];  // [1]
  float* out = (float*)d_out;

  float* U = (float*)d_ws;            // [4096,256]  4 MB
  float* V = U + kRows * kD;          // [4096,256]  4 MB
  float* R = V + kRows * kD;          // [17,256]

  gemm_uv_r<<<513, 256, 0, stream>>>(H, W1, pos_emb, b1, U, V, R);
  const int n_waves = kB * kS * 17;   // 69632 waves, 4 per block
  pair_score<<<n_waves / 4, 256, 0, stream>>>(U, V, R, ln_g, ln_b, W2, b2, out);
}

// Round 3
// 42.659 us; speedup vs baseline: 1.6600x; 1.1894x over previous
//
#include <hip/hip_runtime.h>
#include <math.h>

// Problem constants (fixed by setup_inputs)
constexpr int kB = 32;         // batch
constexpr int kS = 128;        // seq len
constexpr int kD = 256;        // hidden
constexpr int kK = 8;          // window
constexpr int kNPair = 2104;   // pairs with |j-i|<=8
constexpr int kInDim = 2 * kD + 64;  // 576
constexpr int kRows = kB * kS;       // 4096

typedef __attribute__((ext_vector_type(8))) short short8;   // 8 bf16 (4 VGPRs)
typedef __attribute__((ext_vector_type(4))) float f32x4;    // MFMA C/D frag

// f32 -> bf16, round-to-nearest-even
__device__ inline ushort f2b(float f) {
  union { float f; uint u; } v; v.f = f;
  uint r = v.u + 0x7FFF + ((v.u >> 16) & 1);
  return (ushort)(r >> 16);
}

// ---------------------------------------------------------------------------
// Kernel AB (fused): blocks 0..511 do the bf16-MFMA GEMM
//   C[4096][512] = H[4096][256] x Wcat[512][256]^T   (U = cols 0:256, V = rest)
// block 512 computes R[t][d] = sum_u (128-|u-8|)*exp(-(t-u)^2)*(pos_emb[u].W1c[d]) + b1[d]
// ---------------------------------------------------------------------------
__global__ __launch_bounds__(256) void gemm_uv_r(
    const float* __restrict__ H, const float* __restrict__ W1,
    const float* __restrict__ pos_emb, const float* __restrict__ b1,
    float* __restrict__ U, float* __restrict__ V, float* __restrict__ R) {
  __shared__ ushort As[64 * 256];   // 32 KB
  __shared__ ushort Bs[64 * 256];   // 32 KB
  const int tid = threadIdx.x;

  if (blockIdx.x == 512) {
    // ---- build_R (one block) ----
    float* pe = (float*)As;  // 17*64 floats, reuse LDS
    for (int idx = tid; idx < 17 * 64; idx += 256) pe[idx] = pos_emb[idx];
    __syncthreads();
    const int d = tid;
    float w[64];
    const float* wr = W1 + d * kInDim + 2 * kD;
#pragma unroll
    for (int q = 0; q < 16; ++q) {
      float4 t4 = *(const float4*)(wr + q * 4);
      w[q * 4 + 0] = t4.x; w[q * 4 + 1] = t4.y;
      w[q * 4 + 2] = t4.z; w[q * 4 + 3] = t4.w;
    }
    float acc[17];
#pragma unroll
    for (int t = 0; t < 17; ++t) acc[t] = 0.f;
    for (int u = 0; u < 17; ++u) {
      float m = 0.f;
#pragma unroll
      for (int p = 0; p < 64; ++p) m += pe[u * 64 + p] * w[p];
      int au = u - kK; if (au < 0) au = -au;
      m *= (float)(kS - au);
#pragma unroll
      for (int t = 0; t < 17; ++t) {
        int dd = t - u;
        acc[t] += expf((float)(-(dd * dd))) * m;
      }
    }
#pragma unroll
    for (int t = 0; t < 17; ++t) R[t * kD + d] = acc[t] + b1[d];
    return;
  }

  // ---- GEMM ----
  const int mt = blockIdx.x & 63;       // M tile (64 rows of H)
  const int nt = blockIdx.x >> 6;       // N tile (64 output cols of 512)
  const int m0 = mt * 64;
  const int side = (nt >= 4) ? kD : 0;  // U-half vs V-half of W1 rows
  const int wbase = (nt & 3) * 64;      // W1 row base within the 256

  // f32 global -> bf16 LDS, XOR-swizzled so ds_read_b128 column slices are ~2-way
#pragma unroll
  for (int l = 0; l < 16; ++l) {
    int c = tid + l * 256;       // 0..4095 float4-chunks
    int row = c >> 6;            // 0..63
    int kq = (c & 63) << 2;      // element offset 0..252
    int sw = (row << 8) + (kq ^ ((row & 7) << 3));
    float4 a4 = *(const float4*)(H + (m0 + row) * kD + kq);
    ushort4 au; au.x = f2b(a4.x); au.y = f2b(a4.y); au.z = f2b(a4.z); au.w = f2b(a4.w);
    *(ushort4*)(As + sw) = au;
    float4 b4 = *(const float4*)(W1 + (wbase + row) * kInDim + side + kq);
    ushort4 bu; bu.x = f2b(b4.x); bu.y = f2b(b4.y); bu.z = f2b(b4.z); bu.w = f2b(b4.w);
    *(ushort4*)(Bs + sw) = bu;
  }
  __syncthreads();

  const int lane = tid & 63;
  const int w = tid >> 6;            // wave 0..3
  const int wm = (w & 1) * 32;
  const int wn = (w >> 1) * 32;
  const int lr = lane & 15;
  const int lk = (lane >> 4) * 8;

  f32x4 acc[2][2] = {{{0.f,0.f,0.f,0.f},{0.f,0.f,0.f,0.f}},
                     {{0.f,0.f,0.f,0.f},{0.f,0.f,0.f,0.f}}};
#pragma unroll
  for (int kk = 0; kk < 8; ++kk) {
    const int k0 = kk * 32 + lk;
    short8 a[2], b[2];
#pragma unroll
    for (int mf = 0; mf < 2; ++mf) {
      int ra = wm + mf * 16 + lr;
      a[mf] = *(const short8*)(const void*)(As + (ra << 8) + (k0 ^ ((ra & 7) << 3)));
      int rb = wn + mf * 16 + lr;
      b[mf] = *(const short8*)(const void*)(Bs + (rb << 8) + (k0 ^ ((rb & 7) << 3)));
    }
#pragma unroll
    for (int mf = 0; mf < 2; ++mf)
#pragma unroll
      for (int nf = 0; nf < 2; ++nf)
        acc[mf][nf] = __builtin_amdgcn_mfma_f32_16x16x32_bf16(a[mf], b[nf], acc[mf][nf], 0, 0, 0);
  }

  // C/D frag mapping: col = lane&15, row = (lane>>4)*4 + reg
  const int rowg0 = m0 + wm + (lane >> 4) * 4;
  const int colg0 = nt * 64 + wn + lr;
#pragma unroll
  for (int mf = 0; mf < 2; ++mf)
#pragma unroll
    for (int nf = 0; nf < 2; ++nf) {
      int colg = colg0 + nf * 16;
      float* dst = (colg < kD) ? (U + colg) : (V + (colg - kD));
#pragma unroll
      for (int r = 0; r < 4; ++r) {
        int rowg = rowg0 + mf * 16 + r;
        dst[rowg * kD] = acc[mf][nf][r];
      }
    }
}

// ---------------------------------------------------------------------------
// Kernel C v2: one 16-lane group per pair (4 pairs/wave).
// Lane owns 16 elements at d = q*64 + l16*4 (q=0..3) -> coalesced 256B/inst.
// Reductions are 4-step __shfl_xor (8,4,2,1). ELU via hardware __expf.
// ---------------------------------------------------------------------------
__global__ __launch_bounds__(256) void pair_score2(
    const float* __restrict__ U, const float* __restrict__ V,
    const float* __restrict__ R,
    const float* __restrict__ ln_g, const float* __restrict__ ln_b,
    const float* __restrict__ W2, const float* __restrict__ b2,
    float* __restrict__ out) {
  const int tid = threadIdx.x;
  const int l16 = tid & 15;
  const int grp = (blockIdx.x * 256 + tid) >> 4;   // 16-lane group id
  const int t = grp % 17;                          // rel + 8
  const int bi = grp / 17;
  const int i = bi & (kS - 1);
  const int b = bi >> 7;                           // 0..31 by construction
  const int j = i - kK + t;
  const bool valid = (j >= 0) && (j < kS);
  const int jc = valid ? j : 0;

  // closed-form pair index p
  int start_i;
  if (i <= 8)        start_i = (i * i + 17 * i) / 2;
  else if (i <= 120) start_i = 100 + (i - 8) * 17;
  else { int m = i - 120; start_i = 2004 + 16 * m - (m * (m - 1)) / 2; }
  const int lower = (i - kK > 0) ? (i - kK) : 0;
  const int p = start_i + (j - lower);

  const float* Urow = U + (b * kS + i) * kD;
  const float* Vrow = V + (b * kS + jc) * kD;
  const float* Rrow = R + t * kD;

  float h[16];
  float s = 0.f, qs = 0.f;
#pragma unroll
  for (int q = 0; q < 4; ++q) {
    const int d = q * 64 + l16 * 4;
    float4 u4 = *(const float4*)(Urow + d);
    float4 v4 = *(const float4*)(Vrow + d);
    float4 r4 = *(const float4*)(Rrow + d);
    float h0 = u4.x + v4.x + r4.x;
    float h1 = u4.y + v4.y + r4.y;
    float h2 = u4.z + v4.z + r4.z;
    float h3 = u4.w + v4.w + r4.w;
    h[q * 4 + 0] = h0; h[q * 4 + 1] = h1; h[q * 4 + 2] = h2; h[q * 4 + 3] = h3;
    s += h0 + h1 + h2 + h3;
    qs += h0 * h0 + h1 * h1 + h2 * h2 + h3 * h3;
  }
#pragma unroll
  for (int off = 8; off > 0; off >>= 1) {
    s  += __shfl_xor(s, off);
    qs += __shfl_xor(qs, off);
  }
  const float mu = s * (1.0f / kD);
  const float var = qs * (1.0f / kD) - mu * mu;
  const float rs = rsqrtf(var + 1e-5f);

  float dot = 0.f;
#pragma unroll
  for (int q = 0; q < 4; ++q) {
    const int d = q * 64 + l16 * 4;
    float4 g4  = *(const float4*)(ln_g + d);
    float4 be4 = *(const float4*)(ln_b + d);
    float4 w4  = *(const float4*)(W2 + d);
    float y0 = (h[q * 4 + 0] - mu) * rs * g4.x + be4.x;
    float y1 = (h[q * 4 + 1] - mu) * rs * g4.y + be4.y;
    float y2 = (h[q * 4 + 2] - mu) * rs * g4.z + be4.z;
    float y3 = (h[q * 4 + 3] - mu) * rs * g4.w + be4.w;
    y0 = y0 > 0.f ? y0 : (__expf(y0) - 1.0f);   // elu (alpha=1), hw exp
    y1 = y1 > 0.f ? y1 : (__expf(y1) - 1.0f);
    y2 = y2 > 0.f ? y2 : (__expf(y2) - 1.0f);
    y3 = y3 > 0.f ? y3 : (__expf(y3) - 1.0f);
    dot += y0 * w4.x + y1 * w4.y + y2 * w4.z + y3 * w4.w;
  }
#pragma unroll
  for (int off = 8; off > 0; off >>= 1) dot += __shfl_xor(dot, off);

  if (l16 == 0 && valid) {
    out[b * kNPair + p] = dot + b2[0];
    if (b == 0) {
      float* posout = out + kB * kNPair;   // positions read back as f32
      posout[p * 2 + 0] = (float)(i + 1);
      posout[p * 2 + 1] = (float)(j + 1);
    }
  }
}

// ---------------------------------------------------------------------------
extern "C" void kernel_launch(void* const* d_in, const int* in_sizes, int n_in,
                              void* d_out, int out_size, void* d_ws, size_t ws_size,
                              hipStream_t stream) {
  const float* H       = (const float*)d_in[0];  // [32,128,256]
  const float* pos_emb = (const float*)d_in[1];  // [17,64]
  const float* W1      = (const float*)d_in[2];  // [256,576]
  const float* b1      = (const float*)d_in[3];  // [256]
  const float* ln_g    = (const float*)d_in[4];  // [256]
  const float* ln_b    = (const float*)d_in[5];  // [256]
  const float* W2      = (const float*)d_in[6];  // [1,256]
  const float* b2      = (const float*)d_in[7];  // [1]
  float* out = (float*)d_out;

  float* U = (float*)d_ws;            // [4096,256]  4 MB
  float* V = U + kRows * kD;          // [4096,256]  4 MB
  float* R = V + kRows * kD;          // [17,256]

  gemm_uv_r<<<513, 256, 0, stream>>>(H, W1, pos_emb, b1, U, V, R);
  const int n_groups = kB * kS * 17;  // 69632 pair-slots, 16 per block
  pair_score2<<<n_groups / 16, 256, 0, stream>>>(U, V, R, ln_g, ln_b, W2, b2, out);
}

// Round 4
// 39.954 us; speedup vs baseline: 1.7724x; 1.0677x over previous
//
#include <hip/hip_runtime.h>
#include <math.h>

// Problem constants (fixed by setup_inputs)
constexpr int kB = 32;         // batch
constexpr int kS = 128;        // seq len
constexpr int kD = 256;        // hidden
constexpr int kK = 8;          // window
constexpr int kNPair = 2104;   // pairs with |j-i|<=8
constexpr int kInDim = 576;    // 2D + P
constexpr int kRS = 264;       // padded f32 LDS row stride (264 % 32 == 8 -> bank-stagger)

typedef __attribute__((ext_vector_type(8))) short short8;   // 8 bf16 (4 VGPRs)
typedef __attribute__((ext_vector_type(4))) float f32x4;    // MFMA C/D frag

// f32 -> bf16, round-to-nearest-even
__device__ inline ushort f2b(float f) {
  union { float f; uint u; } v; v.f = f;
  uint r = v.u + 0x7FFF + ((v.u >> 16) & 1);
  return (ushort)(r >> 16);
}

// ---------------------------------------------------------------------------
// ONE fused kernel. Block = (batch b, 16-row i-chunk). 256 threads = 4 waves.
// Phases: stage(H window, W1c, params, Kpe) -> R = Kpe @ W1c^T (MFMA) ->
// 8x { stage W n-tile -> MFMA U/V into LDS } -> pair phase from LDS.
// No workspace, single dispatch.
// ---------------------------------------------------------------------------
__global__ __launch_bounds__(256, 1) void fused_all(
    const float* __restrict__ H, const float* __restrict__ pos_emb,
    const float* __restrict__ W1, const float* __restrict__ b1,
    const float* __restrict__ ln_g, const float* __restrict__ ln_b,
    const float* __restrict__ W2, const float* __restrict__ b2,
    float* __restrict__ out) {
  __shared__ __align__(16) ushort sH[48 * 256];    // 24 KB: H window rows (bf16, XOR-swz)
  __shared__ __align__(16) ushort sW[64 * 256];    // 32 KB: W n-tile; first reused as W1c[256][64]
  __shared__ __align__(16) ushort sKpe[32 * 64];   //  4 KB: kernel-weighted pos_emb (A-operand)
  __shared__ float sU[16 * kRS];                   // ~17 KB
  __shared__ float sV[48 * kRS];                   // ~51 KB
  __shared__ float sR[17 * kRS];                   // ~18 KB
  __shared__ float sG[256], sBe[256], sWo[256], sB1[256];
  __shared__ float sB2v;

  const int tid = threadIdx.x;
  const int b = blockIdx.x >> 3;
  const int i0 = (blockIdx.x & 7) << 4;            // i-chunk start
  int ws_ = i0 - 16; if (ws_ < 0) ws_ = 0; if (ws_ > 80) ws_ = 80;
  const int ws = ws_;                              // window start (48 rows, all in-bounds)
  const int oi = i0 - ws;                          // i-chunk offset within window

  // ---- phase 0: params + H window + W1c + Kpe ----
  sG[tid] = ln_g[tid]; sBe[tid] = ln_b[tid]; sWo[tid] = W2[tid]; sB1[tid] = b1[tid];
  if (tid == 0) sB2v = b2[0];

#pragma unroll
  for (int l = 0; l < 12; ++l) {                   // 48 rows x 64 float4-chunks
    int c = tid + l * 256, row = c >> 6, kq = (c & 63) << 2;
    float4 a4 = *(const float4*)(H + (b * kS + ws + row) * kD + kq);
    ushort4 u; u.x = f2b(a4.x); u.y = f2b(a4.y); u.z = f2b(a4.z); u.w = f2b(a4.w);
    *(ushort4*)&sH[row * 256 + (kq ^ ((row & 7) << 3))] = u;
  }
#pragma unroll
  for (int l = 0; l < 16; ++l) {                   // W1c: 256 rows x 16 float4-chunks of 64
    int c = tid + l * 256, d = c >> 4, kq = (c & 15) << 2;
    float4 a4 = *(const float4*)(W1 + d * kInDim + 512 + kq);
    ushort4 u; u.x = f2b(a4.x); u.y = f2b(a4.y); u.z = f2b(a4.z); u.w = f2b(a4.w);
    *(ushort4*)&sW[d * 64 + (kq ^ ((d & 7) << 3))] = u;
  }
  {
    const int pg = (tid & 15) << 2;
#pragma unroll
    for (int pass = 0; pass < 2; ++pass) {
      int t = (tid >> 4) + pass * 16;              // 0..31 (rows >=17 zeroed)
      float a0 = 0.f, a1 = 0.f, a2 = 0.f, a3 = 0.f;
      if (t < 17) {
        for (int u = 0; u < 17; ++u) {
          int du = t - u, au = u - kK; if (au < 0) au = -au;
          float wt = __expf((float)(-(du * du))) * (float)(kS - au);
          float4 pe = *(const float4*)(pos_emb + u * 64 + pg);
          a0 += wt * pe.x; a1 += wt * pe.y; a2 += wt * pe.z; a3 += wt * pe.w;
        }
      }
      ushort4 u; u.x = f2b(a0); u.y = f2b(a1); u.z = f2b(a2); u.w = f2b(a3);
      *(ushort4*)&sKpe[t * 64 + (pg ^ ((t & 7) << 3))] = u;
    }
  }
  __syncthreads();

  const int lane = tid & 63;
  const int w = tid >> 6;                          // wave 0..3
  const int lr = lane & 15;
  const int lk = (lane >> 4) << 3;
  const int swz = (lr & 7) << 3;                   // row&7 == lr&7 for all 16-mult row bases
  const int r0 = (lane >> 4) << 2;

  // ---- phase 1: R[17][256] = Kpe @ W1c^T + b1 (MFMA, K=64) ----
  {
    f32x4 racc[2][4] = {{{0,0,0,0},{0,0,0,0},{0,0,0,0},{0,0,0,0}},
                        {{0,0,0,0},{0,0,0,0},{0,0,0,0},{0,0,0,0}}};
#pragma unroll
    for (int kk = 0; kk < 2; ++kk) {
      int k0 = (kk << 5) + lk;
      short8 a0 = *(const short8*)(const void*)&sKpe[lr * 64 + (k0 ^ swz)];
      short8 a1 = *(const short8*)(const void*)&sKpe[(16 + lr) * 64 + (k0 ^ swz)];
#pragma unroll
      for (int n = 0; n < 4; ++n) {
        int drow = ((w << 2) + n) * 16 + lr;
        short8 bf = *(const short8*)(const void*)&sW[drow * 64 + (k0 ^ swz)];
        racc[0][n] = __builtin_amdgcn_mfma_f32_16x16x32_bf16(a0, bf, racc[0][n], 0, 0, 0);
        racc[1][n] = __builtin_amdgcn_mfma_f32_16x16x32_bf16(a1, bf, racc[1][n], 0, 0, 0);
      }
    }
#pragma unroll
    for (int m = 0; m < 2; ++m)
#pragma unroll
      for (int r = 0; r < 4; ++r) {
        int t = m * 16 + r0 + r;
        if (t < 17) {
#pragma unroll
          for (int n = 0; n < 4; ++n) {
            int d = ((w << 2) + n) * 16 + lr;
            sR[t * kRS + d] = racc[m][n][r] + sB1[d];
          }
        }
      }
  }
  __syncthreads();

  // ---- phase 2: U/V GEMM, 8 n-tiles of 64 cols over 512 ----
  for (int nt = 0; nt < 8; ++nt) {
#pragma unroll
    for (int l = 0; l < 16; ++l) {                 // stage 64 rows x 256 K
      int c = tid + l * 256, row = c >> 6, kq = (c & 63) << 2;
      int cg = (nt << 6) + row;
      const float* src = W1 + (cg & 255) * kInDim + ((cg < 256) ? 0 : 256) + kq;
      float4 a4 = *(const float4*)src;
      ushort4 u; u.x = f2b(a4.x); u.y = f2b(a4.y); u.z = f2b(a4.z); u.w = f2b(a4.w);
      *(ushort4*)&sW[row * 256 + (kq ^ ((row & 7) << 3))] = u;
    }
    __syncthreads();
    f32x4 acc[3] = {{0,0,0,0},{0,0,0,0},{0,0,0,0}};
    const int brow = (w << 4) + lr;
#pragma unroll
    for (int kk = 0; kk < 8; ++kk) {
      int k0 = (kk << 5) + lk;
      short8 bf = *(const short8*)(const void*)&sW[brow * 256 + (k0 ^ swz)];
#pragma unroll
      for (int m = 0; m < 3; ++m) {
        short8 af = *(const short8*)(const void*)&sH[(m * 16 + lr) * 256 + (k0 ^ swz)];
        acc[m] = __builtin_amdgcn_mfma_f32_16x16x32_bf16(af, bf, acc[m], 0, 0, 0);
      }
    }
    const int cg = (nt << 6) + (w << 4) + lr;      // global col 0..511
#pragma unroll
    for (int m = 0; m < 3; ++m)
#pragma unroll
      for (int r = 0; r < 4; ++r) {
        int rw = m * 16 + r0 + r;                  // window row 0..47
        float val = acc[m][r];
        if (cg < 256) {
          unsigned ur = (unsigned)(rw - oi);
          if (ur < 16u) sU[ur * kRS + cg] = val;
        } else {
          sV[rw * kRS + (cg - 256)] = val;
        }
      }
    __syncthreads();
  }

  // ---- phase 3: pair scores from LDS. 16 groups x 17 slots ----
  const int g = tid >> 4, l16 = tid & 15;
  float4 Gp[4], Bp[4], Wp[4];
#pragma unroll
  for (int q = 0; q < 4; ++q) {
    int d = (q << 6) + (l16 << 2);
    Gp[q] = *(const float4*)&sG[d];
    Bp[q] = *(const float4*)&sBe[d];
    Wp[q] = *(const float4*)&sWo[d];
  }
  const float bias2 = sB2v;

  for (int s = g; s < 272; s += 16) {
    int ir = s / 17, t = s - ir * 17;
    int i = i0 + ir, j = i - kK + t;
    if (j < 0 || j >= kS) continue;                // group-uniform
    int vr = j - ws;
    int start_i;
    if (i <= 8)        start_i = (i * i + 17 * i) / 2;
    else if (i <= 120) start_i = 100 + (i - 8) * 17;
    else { int m = i - 120; start_i = 2004 + 16 * m - (m * (m - 1)) / 2; }
    const int lower = (i - kK > 0) ? (i - kK) : 0;
    const int p = start_i + (j - lower);

    const float* Ur = &sU[ir * kRS];
    const float* Vr = &sV[vr * kRS];
    const float* Rr = &sR[t * kRS];
    float h[16]; float ssum = 0.f, qsum = 0.f;
#pragma unroll
    for (int q = 0; q < 4; ++q) {
      int d = (q << 6) + (l16 << 2);
      float4 u4 = *(const float4*)(Ur + d);
      float4 v4 = *(const float4*)(Vr + d);
      float4 r4 = *(const float4*)(Rr + d);
      float h0 = u4.x + v4.x + r4.x;
      float h1 = u4.y + v4.y + r4.y;
      float h2 = u4.z + v4.z + r4.z;
      float h3 = u4.w + v4.w + r4.w;
      h[q * 4 + 0] = h0; h[q * 4 + 1] = h1; h[q * 4 + 2] = h2; h[q * 4 + 3] = h3;
      ssum += h0 + h1 + h2 + h3;
      qsum += h0 * h0 + h1 * h1 + h2 * h2 + h3 * h3;
    }
#pragma unroll
    for (int off = 8; off > 0; off >>= 1) {
      ssum += __shfl_xor(ssum, off);
      qsum += __shfl_xor(qsum, off);
    }
    const float mu = ssum * (1.0f / kD);
    const float var = qsum * (1.0f / kD) - mu * mu;
    const float rs = rsqrtf(var + 1e-5f);
    float dot = 0.f;
#pragma unroll
    for (int q = 0; q < 4; ++q) {
      float y0 = (h[q * 4 + 0] - mu) * rs * Gp[q].x + Bp[q].x;
      float y1 = (h[q * 4 + 1] - mu) * rs * Gp[q].y + Bp[q].y;
      float y2 = (h[q * 4 + 2] - mu) * rs * Gp[q].z + Bp[q].z;
      float y3 = (h[q * 4 + 3] - mu) * rs * Gp[q].w + Bp[q].w;
      y0 = y0 > 0.f ? y0 : (__expf(y0) - 1.0f);
      y1 = y1 > 0.f ? y1 : (__expf(y1) - 1.0f);
      y2 = y2 > 0.f ? y2 : (__expf(y2) - 1.0f);
      y3 = y3 > 0.f ? y3 : (__expf(y3) - 1.0f);
      dot += y0 * Wp[q].x + y1 * Wp[q].y + y2 * Wp[q].z + y3 * Wp[q].w;
    }
#pragma unroll
    for (int off = 8; off > 0; off >>= 1) dot += __shfl_xor(dot, off);

    if (l16 == 0) {
      out[b * kNPair + p] = dot + bias2;
      if (b == 0) {
        float* po = out + kB * kNPair;             // positions read back as f32
        po[2 * p + 0] = (float)(i + 1);
        po[2 * p + 1] = (float)(j + 1);
      }
    }
  }
}

// ---------------------------------------------------------------------------
extern "C" void kernel_launch(void* const* d_in, const int* in_sizes, int n_in,
                              void* d_out, int out_size, void* d_ws, size_t ws_size,
                              hipStream_t stream) {
  (void)in_sizes; (void)n_in; (void)d_ws; (void)ws_size; (void)out_size;
  const float* H       = (const float*)d_in[0];  // [32,128,256]
  const float* pos_emb = (const float*)d_in[1];  // [17,64]
  const float* W1      = (const float*)d_in[2];  // [256,576]
  const float* b1      = (const float*)d_in[3];  // [256]
  const float* ln_g    = (const float*)d_in[4];  // [256]
  const float* ln_b    = (const float*)d_in[5];  // [256]
  const float* W2      = (const float*)d_in[6];  // [1,256]
  const float* b2      = (const float*)d_in[7];  // [1]
  float* out = (float*)d_out;

  fused_all<<<kB * 8, 256, 0, stream>>>(H, pos_emb, W1, b1, ln_g, ln_b, W2, b2, out);
}